// Round 21
// baseline (63.076 us; speedup 1.0000x reference)
//
#include <hip/hip_runtime.h>
#include <hip/hip_bf16.h>

#define KT 576   // CIN*9, GEMM k-order k' = (p*3+q)*64 + c

typedef __attribute__((ext_vector_type(8))) short  short8;
typedef __attribute__((ext_vector_type(4))) float  f32x4;

#define VMCNT(n) asm volatile("s_waitcnt vmcnt(" #n ")" ::: "memory")
#define SB() __builtin_amdgcn_sched_barrier(0)

__device__ __forceinline__ unsigned short f2bf(float f) {
  union { float f; unsigned int u; } v; v.f = f;
  return (unsigned short)((v.u + 0x7FFFu + ((v.u >> 16) & 1u)) >> 16);  // RNE
}

// ---------------------------------------------------------------------------
// Pre-pass: xC2 bf16, layout [hp 34][wp 34][bb 8][cs 8][bl 16][cl 8].
// ---------------------------------------------------------------------------
__global__ __launch_bounds__(256) void xC2_kernel(const float* __restrict__ x,
                                                  unsigned short* __restrict__ xC2) {
  const int hp = blockIdx.x, bb = blockIdx.y, t = threadIdx.x;
  __shared__ unsigned short tile[32 * 1024];   // [w 32][cs 8][bl 16][cl 8]
  const bool interior = (hp >= 1 && hp <= 32);
  if (interior) {
#pragma unroll 4
    for (int i = 0; i < 32; ++i) {
      const int row = i * 32 + (t >> 3);       // = bl*64 + c
      const int bl = row >> 6, c = row & 63;
      const int k = t & 7;
      const float4 v = *(const float4*)(x + ((size_t)(bb * 16 + bl) * 64 + c) * 1024 +
                                        (hp - 1) * 32 + k * 4);
      const int base = (k * 4) * 1024 + (c >> 3) * 128 + bl * 8 + (c & 7);
      tile[base]        = f2bf(v.x);
      tile[base + 1024] = f2bf(v.y);
      tile[base + 2048] = f2bf(v.z);
      tile[base + 3072] = f2bf(v.w);
    }
  }
  __syncthreads();
  unsigned short* dst = xC2 + (size_t)hp * 278528 + (size_t)bb * 1024;
  const uint4 z = make_uint4(0u, 0u, 0u, 0u);
  for (int idx = t; idx < 34 * 128; idx += 256) {
    const int wp = idx >> 7, s = idx & 127;
    uint4 v = z;
    if (interior && wp >= 1 && wp <= 32) v = *(const uint4*)&tile[(wp - 1) * 1024 + s * 8];
    *(uint4*)(dst + (size_t)wp * 8192 + s * 8) = v;
  }
}

// ---------------------------------------------------------------------------
// Main: 1024 blocks = (h 32) x (wq 8) x (quad 4); 256 thr (4 waves, b-tiles).
// QUAD d-SPLIT for TLP: 16 d per block -> acc 32 regs, wreg[3], As 48 ->
// ~110 arch + 32 acc = ~145 total, 2-3 waves/SIMD spill-free (R18's cap
// failure closed); LDS 37 KB -> 4 blocks/CU. XCD swizzle colocates the 4
// quads of one (h,wq) (A-reads L2-hit) and the 4 wq-sharers of out lines.
// Ledger (walk-verified, in-order retirement; entry invariant [A(6j+2)]=6):
//   nw / nw / 15 | scat-a 12 | nw / 15 | scat-b 12 | nw | scat-c 6
//   tail 12/12/6/0; prologue 6/6/6. Never drains mid-loop.
// ---------------------------------------------------------------------------
__global__ __launch_bounds__(256, 1) void lc_main(const float* __restrict__ Wt,
                                                  const float* __restrict__ bias,
                                                  const unsigned short* __restrict__ xC2,
                                                  float* __restrict__ out) {
  __shared__ unsigned short Wl[2][16 * KT];   // 2 x 18432 B
  __shared__ float blds[64];                  // [j 4][dl 16]

  const int bid = (int)blockIdx.x;
  const int swz = (bid & 7) * 128 + (bid >> 3);   // 128-block chunks per XCD
  const int quad = swz & 3, wq = (swz >> 2) & 7, h = swz >> 5;
  const int t = threadIdx.x, lane = t & 63, wv = t >> 6;
  const int l15 = lane & 15, lg = lane >> 4;

  if (t < 64)
    blds[t] = bias[(quad * 16 + (t & 15)) * 1024 + h * 32 + wq * 4 + (t >> 4)];

  const unsigned short* xA = xC2 + (size_t)wv * 2048 + lg * 128 + l15 * 8;
  const int x7 = l15 & 7;
  const int wrow = l15 * KT;

  f32x4 acc[4][2];
#pragma unroll
  for (int j = 0; j < 4; ++j)
#pragma unroll
    for (int bt = 0; bt < 2; ++bt) acc[j][bt] = (f32x4){0.f, 0.f, 0.f, 0.f};

  short8 As0[3][3], As1[3][3];   // A slots [(j*6+g)%3][s]  (3-deep)
  float4 wreg[3];                // one W batch (3 x dwordx4), reused

#define ISSUE_W3(jj, bb)                                                      \
  {                                                                           \
    const float* ws = Wt + (size_t)(h * 32 + wq * 4 + (jj)) * (64 * KT) +     \
                      (size_t)quad * (16 * KT);                               \
    _Pragma("unroll")                                                         \
    for (int i = 0; i < 3; ++i) {                                             \
      const float4* p = (const float4*)ws + (((bb) * 3 + i) * 256 + t);       \
      asm volatile("global_load_dwordx4 %0, %1, off" : "=v"(wreg[i]) : "v"(p)); \
    }                                                                         \
  }

#define ISSUE_A(K)                                                            \
  {                                                                           \
    _Pragma("unroll")                                                         \
    for (int s = 0; s < 3; ++s) {                                             \
      const int step = ((K) % 6) * 3 + s;                                     \
      const int pq = step >> 1, p = pq / 3, q = pq - p * 3;                   \
      const size_t off = (size_t)(h + p) * 278528 +                           \
                         (size_t)(wq * 4 + (K) / 6 + q) * 8192 + (step & 1) * 512; \
      const short8* p0 = (const short8*)(xA + off);                           \
      const short8* p1 = (const short8*)(xA + off + 1024);                    \
      asm volatile("global_load_dwordx4 %0, %1, off" : "=v"(As0[(K) % 3][s]) : "v"(p0)); \
      asm volatile("global_load_dwordx4 %0, %1, off" : "=v"(As1[(K) % 3][s]) : "v"(p1)); \
    }                                                                         \
  }

  // slot mapping: g = kp>>3 = r*8 + (c>>3); sigma = (g&7)*9 + (g>>3); ^ (d&7)
#define SCATTER3(buf, bb)                                                     \
  {                                                                           \
    _Pragma("unroll")                                                         \
    for (int i = 0; i < 3; ++i) {                                             \
      const int f = ((((bb) * 3) + i) * 256 + t) * 4;                         \
      const int d = (((unsigned)(f >> 6)) * 7282u) >> 16;                     \
      int kn = f - d * 576;                                                   \
      int c = ((unsigned)kn * 7282u) >> 16;                                   \
      int r = kn - c * 9;                                                     \
      const float vv[4] = {wreg[i].x, wreg[i].y, wreg[i].z, wreg[i].w};       \
      _Pragma("unroll")                                                       \
      for (int jx = 0; jx < 4; ++jx) {                                        \
        const int kp = r * 64 + c;                                            \
        const int sigma = ((c >> 3) * 9 + r);                                 \
        const int slot = sigma ^ (d & 7);                                     \
        Wl[buf][d * KT + slot * 8 + (kp & 7)] = f2bf(vv[jx]);                 \
        if (++r == 9) { r = 0; ++c; }                                         \
      }                                                                       \
    }                                                                         \
  }

#define MFMAS(jj, gg)                                                         \
  {                                                                           \
    _Pragma("unroll")                                                         \
    for (int s = 0; s < 3; ++s) {                                             \
      const int sb = ((gg) * 3 + s) * 4 + lg;                                 \
      const int sg = (sb & 7) * 9 + (sb >> 3);                                \
      const short8 b0 = *(const short8*)&Wl[(jj) & 1][wrow + ((sg ^ x7) << 3)]; \
      acc[(jj)][0] = __builtin_amdgcn_mfma_f32_16x16x32_bf16(As0[((jj) * 6 + (gg)) % 3][s], b0, acc[(jj)][0], 0, 0, 0); \
      acc[(jj)][1] = __builtin_amdgcn_mfma_f32_16x16x32_bf16(As1[((jj) * 6 + (gg)) % 3][s], b0, acc[(jj)][1], 0, 0, 0); \
    }                                                                         \
  }

#define STEP(jj, gg, NN) { VMCNT(NN); SB(); MFMAS(jj, gg) }
#define STEPNW(jj, gg)   { SB(); MFMAS(jj, gg) }

  // steady phase jj<3 — walk-verified ledger (see header comment)
#define PHASE(jj)                                                             \
  STEPNW(jj, 0);   ISSUE_A(6 * (jj) + 3); ISSUE_W3((jj) + 1, 0);              \
  STEPNW(jj, 1);   ISSUE_A(6 * (jj) + 4);                                     \
  STEP(jj, 2, 15); ISSUE_A(6 * (jj) + 5);                                     \
    VMCNT(12); SB(); SCATTER3(((jj) + 1) & 1, 0); ISSUE_W3((jj) + 1, 1);      \
  STEPNW(jj, 3);   ISSUE_A(6 * (jj) + 6);                                     \
  STEP(jj, 4, 15); ISSUE_A(6 * (jj) + 7);                                     \
    VMCNT(12); SB(); SCATTER3(((jj) + 1) & 1, 1); ISSUE_W3((jj) + 1, 2);      \
  STEPNW(jj, 5);   ISSUE_A(6 * (jj) + 8);                                     \
    VMCNT(6); SB(); SCATTER3(((jj) + 1) & 1, 2);                              \
  __syncthreads(); SB();

  // ---- prologue: W0 via 3 batches of 3; A(0..2) interleaved; exit [A2] ----
  ISSUE_W3(0, 0); ISSUE_A(0);
  VMCNT(6); SB(); SCATTER3(0, 0); ISSUE_W3(0, 1); ISSUE_A(1);
  VMCNT(6); SB(); SCATTER3(0, 1); ISSUE_W3(0, 2); ISSUE_A(2);
  VMCNT(6); SB(); SCATTER3(0, 2);
  __syncthreads(); SB();

  PHASE(0)
  PHASE(1)
  PHASE(2)

  // ---- phase j=3 (no W prefetch; entry queue [A20]=6) ----
  STEPNW(3, 0);   ISSUE_A(21);
  STEPNW(3, 1);   ISSUE_A(22);
  STEP(3, 2, 12); ISSUE_A(23);
  STEP(3, 3, 12);
  STEP(3, 4, 6);
  STEP(3, 5, 0);

  // ---- epilogue: float4 over the 4 consecutive w ----
  {
    const int dg = quad * 16 + l15;
    const float bv0 = blds[l15], bv1 = blds[16 + l15],
                bv2 = blds[32 + l15], bv3 = blds[48 + l15];
#pragma unroll
    for (int bt = 0; bt < 2; ++bt) {
#pragma unroll
      for (int i = 0; i < 4; ++i) {
        const int b = wv * 32 + bt * 16 + lg * 4 + i;
        float4 v;
        v.x = acc[0][bt][i] + bv0;
        v.y = acc[1][bt][i] + bv1;
        v.z = acc[2][bt][i] + bv2;
        v.w = acc[3][bt][i] + bv3;
        *(float4*)(out + (size_t)b * 65536 + (size_t)dg * 1024 + h * 32 + wq * 4) = v;
      }
    }
  }
}

extern "C" void kernel_launch(void* const* d_in, const int* in_sizes, int n_in,
                              void* d_out, int out_size, void* d_ws, size_t ws_size,
                              hipStream_t stream) {
  const float* x    = (const float*)d_in[0];
  const float* wt   = (const float*)d_in[1];
  const float* bias = (const float*)d_in[2];
  float* out        = (float*)d_out;
  unsigned short* xC2 = (unsigned short*)d_ws;   // 18,939,904 B

  xC2_kernel<<<dim3(34, 8), 256, 0, stream>>>(x, xC2);
  lc_main<<<1024, 256, 0, stream>>>(wt, bias, xC2, out);
}

// Round 22
// 62.008 us; speedup vs baseline: 1.0172x; 1.0172x over previous
//
#include <hip/hip_runtime.h>
#include <hip/hip_bf16.h>

#define KT 576   // CIN*9, GEMM k-order k' = (p*3+q)*64 + c

typedef __attribute__((ext_vector_type(8))) short  short8;
typedef __attribute__((ext_vector_type(4))) float  f32x4;

#define VMCNT(n) asm volatile("s_waitcnt vmcnt(" #n ")" ::: "memory")
#define SB() __builtin_amdgcn_sched_barrier(0)

__device__ __forceinline__ unsigned short f2bf(float f) {
  union { float f; unsigned int u; } v; v.f = f;
  return (unsigned short)((v.u + 0x7FFFu + ((v.u >> 16) & 1u)) >> 16);  // RNE
}

// ---------------------------------------------------------------------------
// Pre-pass: xC2 bf16, layout [hp 34][wp 34][bb 8][cs 8][bl 16][cl 8].
// ---------------------------------------------------------------------------
__global__ __launch_bounds__(256) void xC2_kernel(const float* __restrict__ x,
                                                  unsigned short* __restrict__ xC2) {
  const int hp = blockIdx.x, bb = blockIdx.y, t = threadIdx.x;
  __shared__ unsigned short tile[32 * 1024];   // [w 32][cs 8][bl 16][cl 8]
  const bool interior = (hp >= 1 && hp <= 32);
  if (interior) {
#pragma unroll 4
    for (int i = 0; i < 32; ++i) {
      const int row = i * 32 + (t >> 3);       // = bl*64 + c
      const int bl = row >> 6, c = row & 63;
      const int k = t & 7;
      const float4 v = *(const float4*)(x + ((size_t)(bb * 16 + bl) * 64 + c) * 1024 +
                                        (hp - 1) * 32 + k * 4);
      const int base = (k * 4) * 1024 + (c >> 3) * 128 + bl * 8 + (c & 7);
      tile[base]        = f2bf(v.x);
      tile[base + 1024] = f2bf(v.y);
      tile[base + 2048] = f2bf(v.z);
      tile[base + 3072] = f2bf(v.w);
    }
  }
  __syncthreads();
  unsigned short* dst = xC2 + (size_t)hp * 278528 + (size_t)bb * 1024;
  const uint4 z = make_uint4(0u, 0u, 0u, 0u);
  for (int idx = t; idx < 34 * 128; idx += 256) {
    const int wp = idx >> 7, s = idx & 127;
    uint4 v = z;
    if (interior && wp >= 1 && wp <= 32) v = *(const uint4*)&tile[(wp - 1) * 1024 + s * 8];
    *(uint4*)(dst + (size_t)wp * 8192 + s * 8) = v;
  }
}

// ---------------------------------------------------------------------------
// Main: 512 blocks = (h 32) x (wq 8) x (half 2); 256 thr (4 waves, b-tiles).
// Best measured config (R17, 62.1 us): never-drain counted-vmcnt ledger
// (final scatter VMCNT(6) — the verified W-in-flight fix), 2-deep A
// (As[2][3]), W via one wreg[6] in 3 batches, bank-balanced sigma slot
// mapping, XCD-swizzled grid, float4-over-w epilogue.
// ---------------------------------------------------------------------------
__global__ __launch_bounds__(256, 1) void lc_main(const float* __restrict__ Wt,
                                                  const float* __restrict__ bias,
                                                  const unsigned short* __restrict__ xC2,
                                                  float* __restrict__ out) {
  __shared__ unsigned short Wl[2][32 * KT];   // 2 x 36864 B
  __shared__ float blds[128];                 // [j 4][dl 32]

  const int bid = (int)blockIdx.x;
  const int swz = (bid & 7) * 64 + (bid >> 3);    // 64-block chunks per XCD
  const int h = swz >> 4, rem = swz & 15, wq = rem >> 1, half = rem & 1;
  const int t = threadIdx.x, lane = t & 63, wv = t >> 6;
  const int l15 = lane & 15, lg = lane >> 4;

  if (t < 128)
    blds[t] = bias[(half * 32 + (t & 31)) * 1024 + h * 32 + wq * 4 + (t >> 5)];

  const unsigned short* xA = xC2 + (size_t)wv * 2048 + lg * 128 + l15 * 8;
  const int x7 = l15 & 7;
  const int wrow0 = l15 * KT;
  const int wrow1 = (16 + l15) * KT;

  f32x4 acc[4][2][2];
#pragma unroll
  for (int j = 0; j < 4; ++j)
#pragma unroll
    for (int bt = 0; bt < 2; ++bt)
#pragma unroll
      for (int dt = 0; dt < 2; ++dt) acc[j][bt][dt] = (f32x4){0.f, 0.f, 0.f, 0.f};

  short8 As0[2][3], As1[2][3];   // A slots [(j*6+g)%2][s]  (2-deep)
  float4 wreg[6];                // one W batch (6 x dwordx4), reused

#define ISSUE_W6(jj, bb)                                                      \
  {                                                                           \
    const float* ws = Wt + (size_t)(h * 32 + wq * 4 + (jj)) * (64 * KT) +     \
                      (size_t)half * (32 * KT);                               \
    _Pragma("unroll")                                                         \
    for (int i = 0; i < 6; ++i) {                                             \
      const float4* p = (const float4*)ws + (((bb) * 6 + i) * 256 + t);       \
      asm volatile("global_load_dwordx4 %0, %1, off" : "=v"(wreg[i]) : "v"(p)); \
    }                                                                         \
  }

#define ISSUE_A(K)                                                            \
  {                                                                           \
    _Pragma("unroll")                                                         \
    for (int s = 0; s < 3; ++s) {                                             \
      const int step = ((K) % 6) * 3 + s;                                     \
      const int pq = step >> 1, p = pq / 3, q = pq - p * 3;                   \
      const size_t off = (size_t)(h + p) * 278528 +                           \
                         (size_t)(wq * 4 + (K) / 6 + q) * 8192 + (step & 1) * 512; \
      const short8* p0 = (const short8*)(xA + off);                           \
      const short8* p1 = (const short8*)(xA + off + 1024);                    \
      asm volatile("global_load_dwordx4 %0, %1, off" : "=v"(As0[(K) % 2][s]) : "v"(p0)); \
      asm volatile("global_load_dwordx4 %0, %1, off" : "=v"(As1[(K) % 2][s]) : "v"(p1)); \
    }                                                                         \
  }

  // slot mapping: g = kp>>3 = r*8 + (c>>3); sigma = (g&7)*9 + (g>>3); ^ (d&7)
#define SCATTER6(buf, bb)                                                     \
  {                                                                           \
    _Pragma("unroll")                                                         \
    for (int i = 0; i < 6; ++i) {                                             \
      const int f = ((((bb) * 6) + i) * 256 + t) * 4;                         \
      const int d = (((unsigned)(f >> 6)) * 7282u) >> 16;                     \
      int kn = f - d * 576;                                                   \
      int c = ((unsigned)kn * 7282u) >> 16;                                   \
      int r = kn - c * 9;                                                     \
      const float vv[4] = {wreg[i].x, wreg[i].y, wreg[i].z, wreg[i].w};       \
      _Pragma("unroll")                                                       \
      for (int jx = 0; jx < 4; ++jx) {                                        \
        const int kp = r * 64 + c;                                            \
        const int sigma = ((c >> 3) * 9 + r);                                 \
        const int slot = sigma ^ (d & 7);                                     \
        Wl[buf][d * KT + slot * 8 + (kp & 7)] = f2bf(vv[jx]);                 \
        if (++r == 9) { r = 0; ++c; }                                         \
      }                                                                       \
    }                                                                         \
  }

#define MFMAS(jj, gg)                                                         \
  {                                                                           \
    _Pragma("unroll")                                                         \
    for (int s = 0; s < 3; ++s) {                                             \
      const int sb = ((gg) * 3 + s) * 4 + lg;                                 \
      const int sg = (sb & 7) * 9 + (sb >> 3);                                \
      const short8 b0 = *(const short8*)&Wl[(jj) & 1][wrow0 + ((sg ^ x7) << 3)]; \
      const short8 b1 = *(const short8*)&Wl[(jj) & 1][wrow1 + ((sg ^ x7) << 3)]; \
      acc[(jj)][0][0] = __builtin_amdgcn_mfma_f32_16x16x32_bf16(As0[((jj) * 6 + (gg)) % 2][s], b0, acc[(jj)][0][0], 0, 0, 0); \
      acc[(jj)][1][0] = __builtin_amdgcn_mfma_f32_16x16x32_bf16(As1[((jj) * 6 + (gg)) % 2][s], b0, acc[(jj)][1][0], 0, 0, 0); \
      acc[(jj)][0][1] = __builtin_amdgcn_mfma_f32_16x16x32_bf16(As0[((jj) * 6 + (gg)) % 2][s], b1, acc[(jj)][0][1], 0, 0, 0); \
      acc[(jj)][1][1] = __builtin_amdgcn_mfma_f32_16x16x32_bf16(As1[((jj) * 6 + (gg)) % 2][s], b1, acc[(jj)][1][1], 0, 0, 0); \
    }                                                                         \
  }

#define STEP(jj, gg, NN) { VMCNT(NN); SB(); MFMAS(jj, gg) }

  // steady phase jj<3 (walk-verified ledger; final scatter waits VMCNT(6))
#define PHASE(jj)                                                             \
  STEP(jj, 0, 6);  ISSUE_A(6 * (jj) + 2); ISSUE_W6((jj) + 1, 0);              \
  STEP(jj, 1, 12); ISSUE_A(6 * (jj) + 3);                                     \
  STEP(jj, 2, 12); ISSUE_A(6 * (jj) + 4);                                     \
    VMCNT(12); SB(); SCATTER6(((jj) + 1) & 1, 0); ISSUE_W6((jj) + 1, 1);      \
  STEP(jj, 3, 12); ISSUE_A(6 * (jj) + 5);                                     \
  STEP(jj, 4, 12); ISSUE_A(6 * (jj) + 6);                                     \
    VMCNT(12); SB(); SCATTER6(((jj) + 1) & 1, 1); ISSUE_W6((jj) + 1, 2);      \
  STEP(jj, 5, 12); ISSUE_A(6 * (jj) + 7);                                     \
    VMCNT(6); SB(); SCATTER6(((jj) + 1) & 1, 2);                              \
  __syncthreads(); SB();

  // ---- prologue: W0 via 3 batches through wreg[6]; A(0),A(1) issued early ----
  ISSUE_W6(0, 0); ISSUE_A(0); ISSUE_A(1);
  VMCNT(12); SB(); SCATTER6(0, 0); ISSUE_W6(0, 1);
  VMCNT(0);  SB(); SCATTER6(0, 1); ISSUE_W6(0, 2);
  VMCNT(0);  SB(); SCATTER6(0, 2);
  __syncthreads(); SB();

  PHASE(0)
  PHASE(1)
  PHASE(2)

  // ---- phase j=3 (no W prefetch; A 2-deep tail) ----
  STEP(3, 0, 6);  ISSUE_A(20);
  STEP(3, 1, 6);  ISSUE_A(21);
  STEP(3, 2, 6);  ISSUE_A(22);
  STEP(3, 3, 6);  ISSUE_A(23);
  STEP(3, 4, 6);
  STEP(3, 5, 0);

  // ---- epilogue: float4 over the 4 consecutive w ----
#pragma unroll
  for (int dt = 0; dt < 2; ++dt) {
    const int dd = dt * 16 + l15;
    const int dg = half * 32 + dd;
    const float bv0 = blds[dd], bv1 = blds[32 + dd], bv2 = blds[64 + dd], bv3 = blds[96 + dd];
#pragma unroll
    for (int bt = 0; bt < 2; ++bt) {
#pragma unroll
      for (int i = 0; i < 4; ++i) {
        const int b = wv * 32 + bt * 16 + lg * 4 + i;
        float4 v;
        v.x = acc[0][bt][dt][i] + bv0;
        v.y = acc[1][bt][dt][i] + bv1;
        v.z = acc[2][bt][dt][i] + bv2;
        v.w = acc[3][bt][dt][i] + bv3;
        *(float4*)(out + (size_t)b * 65536 + (size_t)dg * 1024 + h * 32 + wq * 4) = v;
      }
    }
  }
}

extern "C" void kernel_launch(void* const* d_in, const int* in_sizes, int n_in,
                              void* d_out, int out_size, void* d_ws, size_t ws_size,
                              hipStream_t stream) {
  const float* x    = (const float*)d_in[0];
  const float* wt   = (const float*)d_in[1];
  const float* bias = (const float*)d_in[2];
  float* out        = (float*)d_out;
  unsigned short* xC2 = (unsigned short*)d_ws;   // 18,939,904 B

  xC2_kernel<<<dim3(34, 8), 256, 0, stream>>>(x, xC2);
  lc_main<<<512, 256, 0, stream>>>(wt, bias, xC2, out);
}